// Round 15
// baseline (209.858 us; speedup 1.0000x reference)
//
#include <hip/hip_runtime.h>

#define NN 50000
#define NE 800000
#define NG 128
#define NF 64
#define EPSV 1e-5f
#define GB3 782     // GEMM blocks = ceil(NN/64)
#define NBUCK 196   // node buckets of 256
#define BCAP 5120   // bucket capacity (mean 4096)
#define OFFMASK 0xFFFFF

typedef unsigned short ushortT;

__device__ inline unsigned short f2bf(float f) {
  unsigned u = __float_as_uint(f);
  u += 0x7FFF + ((u >> 16) & 1);          // round-to-nearest-even
  return (unsigned short)(u >> 16);
}
__device__ inline float bflo(unsigned v) { return __uint_as_float(v << 16); }
__device__ inline float bfhi(unsigned v) { return __uint_as_float(v & 0xFFFF0000u); }

// ============ pre: cvt(x->bf16) + bounds + zero, one launch ============
__global__ __launch_bounds__(256) void k_pre(const float* __restrict__ x,
                                             ushortT* __restrict__ xb,
                                             const int* __restrict__ batch,
                                             int* __restrict__ bound,
                                             int* __restrict__ gcursor,
                                             float* __restrict__ stats) {
  int t = blockIdx.x * 256 + threadIdx.x;
  if (t < NN * NF / 4) {
    float4 v = ((const float4*)x)[t];
    ushort4 o;
    o.x = f2bf(v.x); o.y = f2bf(v.y); o.z = f2bf(v.z); o.w = f2bf(v.w);
    ((ushort4*)xb)[t] = o;
  }
  if (blockIdx.x == 0) {
    int tt = threadIdx.x;
    if (tt < NBUCK) gcursor[tt] = 0;
    for (int k = tt; k < 6 * NG; k += 256) stats[k] = 0.f;
  }
  if (blockIdx.x < (NN + 255) / 256) {
    int i = blockIdx.x * 256 + threadIdx.x;
    if (i < NN) {
      int b1 = batch[i];
      int b0 = (i == 0) ? -1 : batch[i - 1];
      for (int g = b0 + 1; g <= b1; ++g) bound[g] = i;
      if (i == NN - 1) {
        for (int g = b1 + 1; g <= NG; ++g) bound[g] = NN;
      }
    }
  }
}

// ======================= bucketed CSR build (fixed bucket bases) =======================
__global__ __launch_bounds__(256) void k_binA(const int* __restrict__ src,
                                              const int* __restrict__ dst,
                                              int* __restrict__ gcursor,
                                              int2* __restrict__ bbuf) {
  __shared__ int cnt[NBUCK], base[NBUCK], rank[NBUCK];
  int tid = threadIdx.x;
  if (tid < NBUCK) { cnt[tid] = 0; rank[tid] = 0; }
  __syncthreads();
  int e0 = blockIdx.x * 4096;
  int sv[16], dv[16], bk[16];
#pragma unroll
  for (int i = 0; i < 16; ++i) {
    int e = e0 + i * 256 + tid;
    if (e < NE) {
      sv[i] = src[e];
      dv[i] = dst[e];
      bk[i] = dv[i] >> 8;
      atomicAdd(&cnt[bk[i]], 1);
    } else bk[i] = -1;
  }
  __syncthreads();
  if (tid < NBUCK && cnt[tid] > 0)
    base[tid] = tid * BCAP + atomicAdd(&gcursor[tid], cnt[tid]);
  __syncthreads();
#pragma unroll
  for (int i = 0; i < 16; ++i) {
    if (bk[i] >= 0) {
      int p = base[bk[i]] + atomicAdd(&rank[bk[i]], 1);
      if (p < (bk[i] + 1) * BCAP) bbuf[p] = make_int2(sv[i], dv[i]);
    }
  }
}

// per bucket: local count+scan, write packed offdeg, dense csr scatter
__global__ __launch_bounds__(256) void k_binB(const int2* __restrict__ bbuf,
                                              const int* __restrict__ gcursor,
                                              int* __restrict__ offdeg,
                                              int* __restrict__ csr) {
  __shared__ int cnt[256], cur[256], sh[256];
  int tid = threadIdx.x;
  int b = blockIdx.x;
  int nb = gcursor[b]; if (nb > BCAP) nb = BCAP;
  int gbase = b * BCAP;
  cnt[tid] = 0;
  __syncthreads();
  const int2* bp = bbuf + (size_t)gbase;
  for (int i = tid; i < nb; i += 256) {
    atomicAdd(&cnt[bp[i].y & 255], 1);
  }
  __syncthreads();
  int v = cnt[tid];
  sh[tid] = v;
  __syncthreads();
  for (int d = 1; d < 256; d <<= 1) {
    int t = (tid >= d) ? sh[tid - d] : 0;
    __syncthreads();
    sh[tid] += t;
    __syncthreads();
  }
  int excl = sh[tid] - v;
  cur[tid] = excl;
  int node = b * 256 + tid;
  if (node < NN) offdeg[node] = (gbase + excl) | (v << 20);
  __syncthreads();
  for (int i = tid; i < nb; i += 256) {
    int2 e = bp[i];
    int p = atomicAdd(&cur[e.y & 255], 1);
    csr[gbase + p] = e.x;
  }
}

// ============ mean aggregation: bf16 gather, 8 edge-slots x 8 lanes x 16B; bf16 out ============
__global__ __launch_bounds__(256) void k_agg(const ushortT* __restrict__ in,
                                             const int* __restrict__ offdeg,
                                             const int* __restrict__ csr,
                                             ushortT* __restrict__ out) {
  int t = blockIdx.x * 256 + threadIdx.x;
  int node = t >> 6;
  int lane = threadIdx.x & 63;
  int eo = lane >> 3;            // edge slot 0..7
  int fl = (lane & 7) << 3;      // 8-feature base
  if (node >= NN) return;
  int od = offdeg[node];
  int s0 = od & OFFMASK;
  int dg = od >> 20;
  int s1 = s0 + dg;
  float a0 = 0.f, a1 = 0.f, a2 = 0.f, a3 = 0.f, a4 = 0.f, a5 = 0.f, a6 = 0.f, a7 = 0.f;
  for (int j = s0 + eo; j < s1; j += 8) {
    int s = csr[j];
    uint4 v = *(const uint4*)&in[(size_t)s * NF + fl];   // 8 bf16 = 16B
    a0 += bflo(v.x); a1 += bfhi(v.x);
    a2 += bflo(v.y); a3 += bfhi(v.y);
    a4 += bflo(v.z); a5 += bfhi(v.z);
    a6 += bflo(v.w); a7 += bfhi(v.w);
  }
#pragma unroll
  for (int d = 8; d < 64; d <<= 1) {
    a0 += __shfl_xor(a0, d); a1 += __shfl_xor(a1, d);
    a2 += __shfl_xor(a2, d); a3 += __shfl_xor(a3, d);
    a4 += __shfl_xor(a4, d); a5 += __shfl_xor(a5, d);
    a6 += __shfl_xor(a6, d); a7 += __shfl_xor(a7, d);
  }
  if (eo == 0) {
    float inv = (dg > 0) ? 1.f / (float)dg : 0.f;
    uint4 o;
    o.x = (unsigned)f2bf(a0 * inv) | ((unsigned)f2bf(a1 * inv) << 16);
    o.y = (unsigned)f2bf(a2 * inv) | ((unsigned)f2bf(a3 * inv) << 16);
    o.z = (unsigned)f2bf(a4 * inv) | ((unsigned)f2bf(a5 * inv) << 16);
    o.w = (unsigned)f2bf(a6 * inv) | ((unsigned)f2bf(a7 * inv) << 16);
    *(uint4*)&out[(size_t)node * NF + fl] = o;
  }
}

// ============ dual GEMM (bf16 rows): lane=row, 8 waves x 8-col slices; fused LN stats ============
// outf non-null -> fp32 store (final layer); else bf16 store to outb.
__global__ __launch_bounds__(512) void k_sage_linear(const ushortT* __restrict__ A,
                                                     const ushortT* __restrict__ X,
                                                     const float* __restrict__ Wl,
                                                     const float* __restrict__ bl,
                                                     const float* __restrict__ Wr,
                                                     const int* __restrict__ batch,
                                                     float* __restrict__ gsum,
                                                     float* __restrict__ gsq,
                                                     float* __restrict__ outf,
                                                     ushortT* __restrict__ outb) {
  __shared__ float sh_s[8][64];
  __shared__ float sh_q[8][64];
  __shared__ float gs[NG];
  __shared__ float gq[NG];
  int tid = threadIdx.x;
  int lane = tid & 63;
  int wv = __builtin_amdgcn_readfirstlane(tid >> 6);   // 0..7
  int c0 = wv * 8;
  int row = blockIdx.x * 64 + lane;
  bool valid = row < NN;
  if (tid < NG) { gs[tid] = 0.f; gq[tid] = 0.f; }

  float acc[8];
#pragma unroll
  for (int cc = 0; cc < 8; ++cc) acc[cc] = bl[c0 + cc];

  int rsafe = valid ? row : 0;
  const ushortT* Ar = A + (size_t)rsafe * NF;
  const ushortT* Xr = X + (size_t)rsafe * NF;

  for (int k8 = 0; k8 < 8; ++k8) {     // 8 bf16 per 16B load
    uint4 av = *(const uint4*)&Ar[k8 * 8];
    float a0 = bflo(av.x), a1 = bfhi(av.x), a2 = bflo(av.y), a3 = bfhi(av.y);
    float a4 = bflo(av.z), a5 = bfhi(av.z), a6 = bflo(av.w), a7 = bfhi(av.w);
    const float* W0 = Wl + ((k8 * 8 + 0) * NF + c0);
    const float* W1 = Wl + ((k8 * 8 + 1) * NF + c0);
    const float* W2 = Wl + ((k8 * 8 + 2) * NF + c0);
    const float* W3 = Wl + ((k8 * 8 + 3) * NF + c0);
    const float* W4 = Wl + ((k8 * 8 + 4) * NF + c0);
    const float* W5 = Wl + ((k8 * 8 + 5) * NF + c0);
    const float* W6 = Wl + ((k8 * 8 + 6) * NF + c0);
    const float* W7 = Wl + ((k8 * 8 + 7) * NF + c0);
#pragma unroll
    for (int cc = 0; cc < 8; ++cc)
      acc[cc] += a0 * W0[cc] + a1 * W1[cc] + a2 * W2[cc] + a3 * W3[cc]
               + a4 * W4[cc] + a5 * W5[cc] + a6 * W6[cc] + a7 * W7[cc];
  }
  for (int k8 = 0; k8 < 8; ++k8) {
    uint4 xv = *(const uint4*)&Xr[k8 * 8];
    float a0 = bflo(xv.x), a1 = bfhi(xv.x), a2 = bflo(xv.y), a3 = bfhi(xv.y);
    float a4 = bflo(xv.z), a5 = bfhi(xv.z), a6 = bflo(xv.w), a7 = bfhi(xv.w);
    const float* W0 = Wr + ((k8 * 8 + 0) * NF + c0);
    const float* W1 = Wr + ((k8 * 8 + 1) * NF + c0);
    const float* W2 = Wr + ((k8 * 8 + 2) * NF + c0);
    const float* W3 = Wr + ((k8 * 8 + 3) * NF + c0);
    const float* W4 = Wr + ((k8 * 8 + 4) * NF + c0);
    const float* W5 = Wr + ((k8 * 8 + 5) * NF + c0);
    const float* W6 = Wr + ((k8 * 8 + 6) * NF + c0);
    const float* W7 = Wr + ((k8 * 8 + 7) * NF + c0);
#pragma unroll
    for (int cc = 0; cc < 8; ++cc)
      acc[cc] += a0 * W0[cc] + a1 * W1[cc] + a2 * W2[cc] + a3 * W3[cc]
               + a4 * W4[cc] + a5 * W5[cc] + a6 * W6[cc] + a7 * W7[cc];
  }

  if (valid) {
    if (outf) {
      float4* op = (float4*)(outf + (size_t)row * NF + c0);
      op[0] = make_float4(acc[0], acc[1], acc[2], acc[3]);
      op[1] = make_float4(acc[4], acc[5], acc[6], acc[7]);
    } else {
      uint4 b0;
      b0.x = (unsigned)f2bf(acc[0]) | ((unsigned)f2bf(acc[1]) << 16);
      b0.y = (unsigned)f2bf(acc[2]) | ((unsigned)f2bf(acc[3]) << 16);
      b0.z = (unsigned)f2bf(acc[4]) | ((unsigned)f2bf(acc[5]) << 16);
      b0.w = (unsigned)f2bf(acc[6]) | ((unsigned)f2bf(acc[7]) << 16);
      *(uint4*)&outb[(size_t)row * NF + c0] = b0;
    }
  }

  float s = 0.f, q = 0.f;
#pragma unroll
  for (int cc = 0; cc < 8; ++cc) { s += acc[cc]; q += acc[cc] * acc[cc]; }
  sh_s[wv][lane] = s;
  sh_q[wv][lane] = q;
  __syncthreads();
  if (tid < 64) {
    float ss = 0.f, qq = 0.f;
#pragma unroll
    for (int w8 = 0; w8 < 8; ++w8) { ss += sh_s[w8][lane]; qq += sh_q[w8][lane]; }
    int r = blockIdx.x * 64 + lane;
    if (r < NN) {
      int g = batch[r];
      atomicAdd(&gs[g], ss);
      atomicAdd(&gq[g], qq);
    }
  }
  __syncthreads();
  if (tid < NG) {
    float fs = gs[tid], fq = gq[tid];
    if (fs != 0.f || fq != 0.f) { atomicAdd(&gsum[tid], fs); atomicAdd(&gsq[tid], fq); }
  }
}

// ============ skip0: 8 waves x 8-col slices, two sequential passes ============
// pass1: z1b = LN0(t0b)+PReLU + xb@W0 ; pass2: xs1b = xb@W1 (X rows L1-hot)
__global__ __launch_bounds__(512) void k_skip0(
    const ushortT* __restrict__ X,
    const float* __restrict__ W0p, const float* __restrict__ W1p,
    const ushortT* __restrict__ t0b,
    const float* __restrict__ gsum0, const float* __restrict__ gsq0,
    const float* __restrict__ lw0, const float* __restrict__ lb0, const float* __restrict__ pa0,
    const int* __restrict__ batch, const int* __restrict__ bound,
    ushortT* __restrict__ z1b, ushortT* __restrict__ xs1b) {
  int tid = threadIdx.x;
  int lane = tid & 63;
  int wv = __builtin_amdgcn_readfirstlane(tid >> 6);   // 0..7
  int c0 = wv * 8;
  int row = blockIdx.x * 64 + lane;
  bool valid = row < NN;
  int rsafe = valid ? row : 0;
  const ushortT* Xr = X + (size_t)rsafe * NF;

  float acc[8];
#pragma unroll
  for (int cc = 0; cc < 8; ++cc) acc[cc] = 0.f;

  // ---- pass 1: xb @ W0 ----
  for (int k8 = 0; k8 < 8; ++k8) {
    uint4 xv = *(const uint4*)&Xr[k8 * 8];
    float a0 = bflo(xv.x), a1 = bfhi(xv.x), a2 = bflo(xv.y), a3 = bfhi(xv.y);
    float a4 = bflo(xv.z), a5 = bfhi(xv.z), a6 = bflo(xv.w), a7 = bfhi(xv.w);
    const float* P0 = W0p + ((k8 * 8 + 0) * NF + c0);
    const float* P1 = W0p + ((k8 * 8 + 1) * NF + c0);
    const float* P2 = W0p + ((k8 * 8 + 2) * NF + c0);
    const float* P3 = W0p + ((k8 * 8 + 3) * NF + c0);
    const float* P4 = W0p + ((k8 * 8 + 4) * NF + c0);
    const float* P5 = W0p + ((k8 * 8 + 5) * NF + c0);
    const float* P6 = W0p + ((k8 * 8 + 6) * NF + c0);
    const float* P7 = W0p + ((k8 * 8 + 7) * NF + c0);
#pragma unroll
    for (int cc = 0; cc < 8; ++cc)
      acc[cc] += a0 * P0[cc] + a1 * P1[cc] + a2 * P2[cc] + a3 * P3[cc]
               + a4 * P4[cc] + a5 * P5[cc] + a6 * P6[cc] + a7 * P7[cc];
  }

  // LN0 residual + PReLU (8 cols)
  int g = batch[rsafe];
  float cntf = (float)(bound[g + 1] - bound[g]);
  float norm = fmaxf(cntf, 1.f) * (float)NF;
  float m0 = gsum0[g] / norm;
  float v0 = gsq0[g] / norm - m0 * m0;
  float rs0 = rsqrtf(v0 + EPSV);
  float a0p = pa0[0];
  {
    uint4 tv = *(const uint4*)(t0b + (size_t)rsafe * NF + c0);
    float tvv[8] = {bflo(tv.x), bfhi(tv.x), bflo(tv.y), bfhi(tv.y),
                    bflo(tv.z), bfhi(tv.z), bflo(tv.w), bfhi(tv.w)};
#pragma unroll
    for (int jj = 0; jj < 8; ++jj) {
      float u = (tvv[jj] - m0) * rs0 * lw0[c0 + jj] + lb0[c0 + jj];
      acc[jj] += (u >= 0.f) ? u : a0p * u;
    }
  }

  if (valid) {
    uint4 o0;
    o0.x = (unsigned)f2bf(acc[0]) | ((unsigned)f2bf(acc[1]) << 16);
    o0.y = (unsigned)f2bf(acc[2]) | ((unsigned)f2bf(acc[3]) << 16);
    o0.z = (unsigned)f2bf(acc[4]) | ((unsigned)f2bf(acc[5]) << 16);
    o0.w = (unsigned)f2bf(acc[6]) | ((unsigned)f2bf(acc[7]) << 16);
    *(uint4*)&z1b[(size_t)row * NF + c0] = o0;
  }

  // ---- pass 2: xb @ W1 (rows L1-hot) ----
#pragma unroll
  for (int cc = 0; cc < 8; ++cc) acc[cc] = 0.f;
  for (int k8 = 0; k8 < 8; ++k8) {
    uint4 xv = *(const uint4*)&Xr[k8 * 8];
    float a0 = bflo(xv.x), a1 = bfhi(xv.x), a2 = bflo(xv.y), a3 = bfhi(xv.y);
    float a4 = bflo(xv.z), a5 = bfhi(xv.z), a6 = bflo(xv.w), a7 = bfhi(xv.w);
    const float* Q0 = W1p + ((k8 * 8 + 0) * NF + c0);
    const float* Q1 = W1p + ((k8 * 8 + 1) * NF + c0);
    const float* Q2 = W1p + ((k8 * 8 + 2) * NF + c0);
    const float* Q3 = W1p + ((k8 * 8 + 3) * NF + c0);
    const float* Q4 = W1p + ((k8 * 8 + 4) * NF + c0);
    const float* Q5 = W1p + ((k8 * 8 + 5) * NF + c0);
    const float* Q6 = W1p + ((k8 * 8 + 6) * NF + c0);
    const float* Q7 = W1p + ((k8 * 8 + 7) * NF + c0);
#pragma unroll
    for (int cc = 0; cc < 8; ++cc)
      acc[cc] += a0 * Q0[cc] + a1 * Q1[cc] + a2 * Q2[cc] + a3 * Q3[cc]
               + a4 * Q4[cc] + a5 * Q5[cc] + a6 * Q6[cc] + a7 * Q7[cc];
  }
  if (valid) {
    uint4 s0v;
    s0v.x = (unsigned)f2bf(acc[0]) | ((unsigned)f2bf(acc[1]) << 16);
    s0v.y = (unsigned)f2bf(acc[2]) | ((unsigned)f2bf(acc[3]) << 16);
    s0v.z = (unsigned)f2bf(acc[4]) | ((unsigned)f2bf(acc[5]) << 16);
    s0v.w = (unsigned)f2bf(acc[6]) | ((unsigned)f2bf(acc[7]) << 16);
    *(uint4*)&xs1b[(size_t)row * NF + c0] = s0v;
  }
}

// ============ skip1 (elementwise): z2b = PReLU0(LN0(h1b)) + PReLU1(LN1(h2b)) + xs1b ============
__global__ __launch_bounds__(256) void k_skip1(
    const ushortT* __restrict__ h1b, const ushortT* __restrict__ h2b,
    const ushortT* __restrict__ xs1b,
    const float* __restrict__ gsum0, const float* __restrict__ gsq0,
    const float* __restrict__ lw0, const float* __restrict__ lb0, const float* __restrict__ pa0,
    const float* __restrict__ gsum1, const float* __restrict__ gsq1,
    const float* __restrict__ lw1, const float* __restrict__ lb1, const float* __restrict__ pa1,
    const int* __restrict__ batch, const int* __restrict__ bound,
    ushortT* __restrict__ z2b) {
  int t = blockIdx.x * 256 + threadIdx.x;   // one uint4 (8 bf16) per thread
  if (t >= NN * NF / 8) return;
  int row = t >> 3;
  int f0 = (t & 7) * 8;
  int g = batch[row];
  float cntf = (float)(bound[g + 1] - bound[g]);
  float norm = fmaxf(cntf, 1.f) * (float)NF;
  float m0 = gsum0[g] / norm;
  float va0 = gsq0[g] / norm - m0 * m0;
  float rs0 = rsqrtf(va0 + EPSV);
  float m1 = gsum1[g] / norm;
  float va1 = gsq1[g] / norm - m1 * m1;
  float rs1 = rsqrtf(va1 + EPSV);
  float a0 = pa0[0], a1 = pa1[0];
  uint4 h1 = ((const uint4*)h1b)[t];
  uint4 h2 = ((const uint4*)h2b)[t];
  uint4 xs = ((const uint4*)xs1b)[t];
  float r[8];
  float h1v[8] = {bflo(h1.x), bfhi(h1.x), bflo(h1.y), bfhi(h1.y),
                  bflo(h1.z), bfhi(h1.z), bflo(h1.w), bfhi(h1.w)};
  float h2v[8] = {bflo(h2.x), bfhi(h2.x), bflo(h2.y), bfhi(h2.y),
                  bflo(h2.z), bfhi(h2.z), bflo(h2.w), bfhi(h2.w)};
  float xsv[8] = {bflo(xs.x), bfhi(xs.x), bflo(xs.y), bfhi(xs.y),
                  bflo(xs.z), bfhi(xs.z), bflo(xs.w), bfhi(xs.w)};
#pragma unroll
  for (int j = 0; j < 8; ++j) {
    float u = (h1v[j] - m0) * rs0 * lw0[f0 + j] + lb0[f0 + j];
    u = (u >= 0.f) ? u : a0 * u;
    float w = (h2v[j] - m1) * rs1 * lw1[f0 + j] + lb1[f0 + j];
    w = (w >= 0.f) ? w : a1 * w;
    r[j] = u + w + xsv[j];
  }
  uint4 o;
  o.x = (unsigned)f2bf(r[0]) | ((unsigned)f2bf(r[1]) << 16);
  o.y = (unsigned)f2bf(r[2]) | ((unsigned)f2bf(r[3]) << 16);
  o.z = (unsigned)f2bf(r[4]) | ((unsigned)f2bf(r[5]) << 16);
  o.w = (unsigned)f2bf(r[6]) | ((unsigned)f2bf(r[7]) << 16);
  ((uint4*)z2b)[t] = o;
}

// ============ graph LayerNorm apply + affine + PReLU (final layer) ============
__global__ __launch_bounds__(256) void k_ln_apply(const float* __restrict__ t,
                                                  const int* __restrict__ batch,
                                                  const int* __restrict__ bound,
                                                  const float* __restrict__ gsum,
                                                  const float* __restrict__ gsq,
                                                  const float* __restrict__ w,
                                                  const float* __restrict__ b,
                                                  const float* __restrict__ alpha,
                                                  float* __restrict__ out) {
  int wid = (blockIdx.x * 256 + threadIdx.x) >> 6;
  int lane = threadIdx.x & 63;
  if (wid >= NN) return;
  int g = batch[wid];
  float cnt = (float)(bound[g + 1] - bound[g]);
  float norm = fmaxf(cnt, 1.f) * (float)NF;
  float mean = gsum[g] / norm;
  float var = gsq[g] / norm - mean * mean;
  float rstd = rsqrtf(var + EPSV);
  float a = alpha[0];
  float v = t[wid * NF + lane];
  v = (v - mean) * rstd;
  v = v * w[lane] + b[lane];
  out[wid * NF + lane] = (v >= 0.f) ? v : a * v;
}

// ======================= launch =======================
extern "C" void kernel_launch(void* const* d_in, const int* in_sizes, int n_in,
                              void* d_out, int out_size, void* d_ws, size_t ws_size,
                              hipStream_t stream) {
  const float* x     = (const float*)d_in[0];
  const float* c0_Wl = (const float*)d_in[1];
  const float* c0_bl = (const float*)d_in[2];
  const float* c0_Wr = (const float*)d_in[3];
  const float* c1_Wl = (const float*)d_in[4];
  const float* c1_bl = (const float*)d_in[5];
  const float* c1_Wr = (const float*)d_in[6];
  const float* c2_Wl = (const float*)d_in[7];
  const float* c2_bl = (const float*)d_in[8];
  const float* c2_Wr = (const float*)d_in[9];
  const float* s0_W  = (const float*)d_in[10];
  const float* s1_W  = (const float*)d_in[11];
  const float* ln0_w = (const float*)d_in[12];
  const float* ln0_b = (const float*)d_in[13];
  const float* ln1_w = (const float*)d_in[14];
  const float* ln1_b = (const float*)d_in[15];
  const float* ln2_w = (const float*)d_in[16];
  const float* ln2_b = (const float*)d_in[17];
  const float* p0_a  = (const float*)d_in[18];
  const float* p1_a  = (const float*)d_in[19];
  const float* p2_a  = (const float*)d_in[20];
  const int*   ei    = (const int*)d_in[21];   // [2, E] int32
  const int*   batch = (const int*)d_in[22];   // [N] int32
  float* out = (float*)d_out;

  const int* src = ei;
  const int* dst = ei + NE;

  // ---- workspace layout ----
  char* ws = (char*)d_ws;
  const size_t off_gcur   = 0;                          // NBUCK ints
  const size_t off_stats  = 4096;                       // 6*G floats
  const size_t off_bound  = 8192;                       // G+1 ints
  const size_t off_od     = 12288;                      // N ints (packed off|deg)
  const size_t off_csr    = 262144;                     // NBUCK*BCAP ints = 4014080
  const size_t off_bbuf   = 4980736;                    // NBUCK*BCAP int2 = 8028160
  const size_t off_B1b    = off_bbuf;                   // agg out bf16 (aliases bbuf)
  const size_t off_B2b    = 13631488;                   // h1 raw bf16 6.4MB
  const size_t off_B4b    = off_B2b + 6400000;          // h2 raw bf16
  const size_t off_xb     = off_B4b + 6400000;          // x bf16
  const size_t off_B3b    = off_xb + 6400000;           // z bf16
  const size_t off_xs1b   = off_B3b + 6400000;          // x@s1_W bf16

  int*    gcursor = (int*)(ws + off_gcur);
  float*  stats   = (float*)(ws + off_stats);
  int*    bound   = (int*)(ws + off_bound);
  int*    offdeg  = (int*)(ws + off_od);
  int*    csr     = (int*)(ws + off_csr);
  int2*   bbuf    = (int2*)(ws + off_bbuf);
  ushortT* B1b    = (ushortT*)(ws + off_B1b);
  ushortT* B2b    = (ushortT*)(ws + off_B2b);
  ushortT* B4b    = (ushortT*)(ws + off_B4b);
  ushortT* xb     = (ushortT*)(ws + off_xb);
  ushortT* B3b    = (ushortT*)(ws + off_B3b);
  ushortT* xs1b   = (ushortT*)(ws + off_xs1b);
  (void)ws_size; (void)in_sizes; (void)n_in; (void)out_size;

  float* gsum0 = stats + 0 * NG; float* gsq0 = stats + 1 * NG;
  float* gsum1 = stats + 2 * NG; float* gsq1 = stats + 3 * NG;
  float* gsum2 = stats + 4 * NG; float* gsq2 = stats + 5 * NG;

  const int WB  = (NN * 64 + 255) / 256;       // 12500 (wave-per-node)
  const int CB  = (NN * NF / 4 + 255) / 256;   // 3125  (pre)
  const int EWB = (NN * NF / 8 + 255) / 256;   // 1563  (skip1 elementwise)

  // pre (cvt + bounds + zero) and bucketed CSR build
  k_pre<<<CB, 256, 0, stream>>>(x, xb, batch, bound, gcursor, stats);
  k_binA<<<NBUCK, 256, 0, stream>>>(src, dst, gcursor, bbuf);
  k_binB<<<NBUCK, 256, 0, stream>>>(bbuf, gcursor, offdeg, csr);

  // ---- layer 0 ----
  k_agg<<<WB, 256, 0, stream>>>(xb, offdeg, csr, B1b);
  k_sage_linear<<<GB3, 512, 0, stream>>>(B1b, xb, c0_Wl, c0_bl, c0_Wr,
                                         batch, gsum0, gsq0, nullptr, B2b);
  // z1b = LN0(B2b)+PReLU + xb@s0_W ; xs1b = xb@s1_W
  k_skip0<<<GB3, 512, 0, stream>>>(xb, s0_W, s1_W,
                                   B2b, gsum0, gsq0, ln0_w, ln0_b, p0_a,
                                   batch, bound, B3b, xs1b);

  // ---- layer 1 ----
  k_agg<<<WB, 256, 0, stream>>>(B3b, offdeg, csr, B1b);
  k_sage_linear<<<GB3, 512, 0, stream>>>(B1b, B3b, c1_Wl, c1_bl, c1_Wr,
                                         batch, gsum1, gsq1, nullptr, B4b);
  // z2b = PReLU0(LN0(B2b)) + PReLU1(LN1(B4b)) + xs1b
  k_skip1<<<EWB, 256, 0, stream>>>(B2b, B4b, xs1b,
                                   gsum0, gsq0, ln0_w, ln0_b, p0_a,
                                   gsum1, gsq1, ln1_w, ln1_b, p1_a,
                                   batch, bound, B3b);

  // ---- layer 2 ----
  k_agg<<<WB, 256, 0, stream>>>(B3b, offdeg, csr, B1b);
  k_sage_linear<<<GB3, 512, 0, stream>>>(B1b, B3b, c2_Wl, c2_bl, c2_Wr,
                                         batch, gsum2, gsq2, out, nullptr);
  k_ln_apply<<<WB, 256, 0, stream>>>(out, batch, bound, gsum2, gsq2, ln2_w, ln2_b, p2_a, out);
}

// Round 16
// 204.609 us; speedup vs baseline: 1.0257x; 1.0257x over previous
//
#include <hip/hip_runtime.h>

#define NN 50000
#define NE 800000
#define NG 128
#define NF 64
#define EPSV 1e-5f
#define GB3 782     // GEMM blocks = ceil(NN/64)
#define NBUCK 196   // node buckets of 256
#define BCAP 5120   // bucket capacity (mean 4096)
#define OFFMASK 0xFFFFF

typedef unsigned short ushortT;

__device__ inline unsigned short f2bf(float f) {
  unsigned u = __float_as_uint(f);
  u += 0x7FFF + ((u >> 16) & 1);          // round-to-nearest-even
  return (unsigned short)(u >> 16);
}
__device__ inline float bflo(unsigned v) { return __uint_as_float(v << 16); }
__device__ inline float bfhi(unsigned v) { return __uint_as_float(v & 0xFFFF0000u); }

// ============ pre: cvt(x->bf16) + bounds + zero, one launch ============
__global__ __launch_bounds__(256) void k_pre(const float* __restrict__ x,
                                             ushortT* __restrict__ xb,
                                             const int* __restrict__ batch,
                                             int* __restrict__ bound,
                                             int* __restrict__ gcursor,
                                             float* __restrict__ stats) {
  int t = blockIdx.x * 256 + threadIdx.x;
  if (t < NN * NF / 4) {
    float4 v = ((const float4*)x)[t];
    ushort4 o;
    o.x = f2bf(v.x); o.y = f2bf(v.y); o.z = f2bf(v.z); o.w = f2bf(v.w);
    ((ushort4*)xb)[t] = o;
  }
  if (blockIdx.x == 0) {
    int tt = threadIdx.x;
    if (tt < NBUCK) gcursor[tt] = 0;
    for (int k = tt; k < 6 * NG; k += 256) stats[k] = 0.f;
  }
  if (blockIdx.x < (NN + 255) / 256) {
    int i = blockIdx.x * 256 + threadIdx.x;
    if (i < NN) {
      int b1 = batch[i];
      int b0 = (i == 0) ? -1 : batch[i - 1];
      for (int g = b0 + 1; g <= b1; ++g) bound[g] = i;
      if (i == NN - 1) {
        for (int g = b1 + 1; g <= NG; ++g) bound[g] = NN;
      }
    }
  }
}

// ======================= bucketed CSR build (fixed bases, packed 1-int edges) =======================
// packed edge: src (16b, NN<65536) | (dst&255)<<16
__global__ __launch_bounds__(256) void k_binA(const int* __restrict__ src,
                                              const int* __restrict__ dst,
                                              int* __restrict__ gcursor,
                                              int* __restrict__ bbuf) {
  __shared__ int cnt[NBUCK], base[NBUCK], rank[NBUCK];
  int tid = threadIdx.x;
  if (tid < NBUCK) { cnt[tid] = 0; rank[tid] = 0; }
  __syncthreads();
  int e0 = blockIdx.x * 4096;
  int pk[16], bk[16];
#pragma unroll
  for (int i = 0; i < 16; ++i) {
    int e = e0 + i * 256 + tid;
    if (e < NE) {
      int s = src[e];
      int d = dst[e];
      pk[i] = s | ((d & 255) << 16);
      bk[i] = d >> 8;
      atomicAdd(&cnt[bk[i]], 1);
    } else bk[i] = -1;
  }
  __syncthreads();
  if (tid < NBUCK && cnt[tid] > 0)
    base[tid] = tid * BCAP + atomicAdd(&gcursor[tid], cnt[tid]);
  __syncthreads();
#pragma unroll
  for (int i = 0; i < 16; ++i) {
    if (bk[i] >= 0) {
      int p = base[bk[i]] + atomicAdd(&rank[bk[i]], 1);
      if (p < (bk[i] + 1) * BCAP) bbuf[p] = pk[i];
    }
  }
}

// per bucket: local count+scan, write packed offdeg, dense csr scatter
__global__ __launch_bounds__(256) void k_binB(const int* __restrict__ bbuf,
                                              const int* __restrict__ gcursor,
                                              int* __restrict__ offdeg,
                                              int* __restrict__ csr) {
  __shared__ int cnt[256], cur[256], sh[256];
  int tid = threadIdx.x;
  int b = blockIdx.x;
  int nb = gcursor[b]; if (nb > BCAP) nb = BCAP;
  int gbase = b * BCAP;
  cnt[tid] = 0;
  __syncthreads();
  const int* bp = bbuf + (size_t)gbase;
  for (int i = tid; i < nb; i += 256) {
    atomicAdd(&cnt[(bp[i] >> 16) & 255], 1);
  }
  __syncthreads();
  int v = cnt[tid];
  sh[tid] = v;
  __syncthreads();
  for (int d = 1; d < 256; d <<= 1) {
    int t = (tid >= d) ? sh[tid - d] : 0;
    __syncthreads();
    sh[tid] += t;
    __syncthreads();
  }
  int excl = sh[tid] - v;
  cur[tid] = excl;
  int node = b * 256 + tid;
  if (node < NN) offdeg[node] = (gbase + excl) | (v << 20);
  __syncthreads();
  for (int i = tid; i < nb; i += 256) {
    int e = bp[i];
    int p = atomicAdd(&cur[(e >> 16) & 255], 1);
    csr[gbase + p] = e & 0xFFFF;
  }
}

// ============ mean aggregation: bf16 gather, 8 edge-slots x 8 lanes x 16B; bf16 out ============
__global__ __launch_bounds__(256) void k_agg(const ushortT* __restrict__ in,
                                             const int* __restrict__ offdeg,
                                             const int* __restrict__ csr,
                                             ushortT* __restrict__ out) {
  int t = blockIdx.x * 256 + threadIdx.x;
  int node = t >> 6;
  int lane = threadIdx.x & 63;
  int eo = lane >> 3;            // edge slot 0..7
  int fl = (lane & 7) << 3;      // 8-feature base
  if (node >= NN) return;
  int od = offdeg[node];
  int s0 = od & OFFMASK;
  int dg = od >> 20;
  int s1 = s0 + dg;
  float a0 = 0.f, a1 = 0.f, a2 = 0.f, a3 = 0.f, a4 = 0.f, a5 = 0.f, a6 = 0.f, a7 = 0.f;
  for (int j = s0 + eo; j < s1; j += 8) {
    int s = csr[j];
    uint4 v = *(const uint4*)&in[(size_t)s * NF + fl];   // 8 bf16 = 16B
    a0 += bflo(v.x); a1 += bfhi(v.x);
    a2 += bflo(v.y); a3 += bfhi(v.y);
    a4 += bflo(v.z); a5 += bfhi(v.z);
    a6 += bflo(v.w); a7 += bfhi(v.w);
  }
#pragma unroll
  for (int d = 8; d < 64; d <<= 1) {
    a0 += __shfl_xor(a0, d); a1 += __shfl_xor(a1, d);
    a2 += __shfl_xor(a2, d); a3 += __shfl_xor(a3, d);
    a4 += __shfl_xor(a4, d); a5 += __shfl_xor(a5, d);
    a6 += __shfl_xor(a6, d); a7 += __shfl_xor(a7, d);
  }
  if (eo == 0) {
    float inv = (dg > 0) ? 1.f / (float)dg : 0.f;
    uint4 o;
    o.x = (unsigned)f2bf(a0 * inv) | ((unsigned)f2bf(a1 * inv) << 16);
    o.y = (unsigned)f2bf(a2 * inv) | ((unsigned)f2bf(a3 * inv) << 16);
    o.z = (unsigned)f2bf(a4 * inv) | ((unsigned)f2bf(a5 * inv) << 16);
    o.w = (unsigned)f2bf(a6 * inv) | ((unsigned)f2bf(a7 * inv) << 16);
    *(uint4*)&out[(size_t)node * NF + fl] = o;
  }
}

// ============ dual GEMM (bf16 rows): lane=row, 4 waves x 16-col slices; fused LN stats ============
// bf16 store to outb (all layers; final layer's outb -> ln_apply reads it).
__global__ __launch_bounds__(256) void k_sage_linear(const ushortT* __restrict__ A,
                                                     const ushortT* __restrict__ X,
                                                     const float* __restrict__ Wl,
                                                     const float* __restrict__ bl,
                                                     const float* __restrict__ Wr,
                                                     const int* __restrict__ batch,
                                                     float* __restrict__ gsum,
                                                     float* __restrict__ gsq,
                                                     ushortT* __restrict__ outb) {
  __shared__ float sh_s[4][64];
  __shared__ float sh_q[4][64];
  __shared__ float gs[NG];
  __shared__ float gq[NG];
  int tid = threadIdx.x;
  int lane = tid & 63;
  int wv = __builtin_amdgcn_readfirstlane(tid >> 6);
  int c0 = wv * 16;
  int row = blockIdx.x * 64 + lane;
  bool valid = row < NN;
  if (tid < NG) { gs[tid] = 0.f; gq[tid] = 0.f; }

  float acc[16];
#pragma unroll
  for (int cc = 0; cc < 16; ++cc) acc[cc] = bl[c0 + cc];

  int rsafe = valid ? row : 0;
  const ushortT* Ar = A + (size_t)rsafe * NF;
  const ushortT* Xr = X + (size_t)rsafe * NF;

  for (int k8 = 0; k8 < 8; ++k8) {     // 8 bf16 per 16B load
    uint4 av = *(const uint4*)&Ar[k8 * 8];
    float a0 = bflo(av.x), a1 = bfhi(av.x), a2 = bflo(av.y), a3 = bfhi(av.y);
    float a4 = bflo(av.z), a5 = bfhi(av.z), a6 = bflo(av.w), a7 = bfhi(av.w);
    const float* W0 = Wl + ((k8 * 8 + 0) * NF + c0);
    const float* W1 = Wl + ((k8 * 8 + 1) * NF + c0);
    const float* W2 = Wl + ((k8 * 8 + 2) * NF + c0);
    const float* W3 = Wl + ((k8 * 8 + 3) * NF + c0);
    const float* W4 = Wl + ((k8 * 8 + 4) * NF + c0);
    const float* W5 = Wl + ((k8 * 8 + 5) * NF + c0);
    const float* W6 = Wl + ((k8 * 8 + 6) * NF + c0);
    const float* W7 = Wl + ((k8 * 8 + 7) * NF + c0);
#pragma unroll
    for (int cc = 0; cc < 16; ++cc)
      acc[cc] += a0 * W0[cc] + a1 * W1[cc] + a2 * W2[cc] + a3 * W3[cc]
               + a4 * W4[cc] + a5 * W5[cc] + a6 * W6[cc] + a7 * W7[cc];
  }
  for (int k8 = 0; k8 < 8; ++k8) {
    uint4 xv = *(const uint4*)&Xr[k8 * 8];
    float a0 = bflo(xv.x), a1 = bfhi(xv.x), a2 = bflo(xv.y), a3 = bfhi(xv.y);
    float a4 = bflo(xv.z), a5 = bfhi(xv.z), a6 = bflo(xv.w), a7 = bfhi(xv.w);
    const float* W0 = Wr + ((k8 * 8 + 0) * NF + c0);
    const float* W1 = Wr + ((k8 * 8 + 1) * NF + c0);
    const float* W2 = Wr + ((k8 * 8 + 2) * NF + c0);
    const float* W3 = Wr + ((k8 * 8 + 3) * NF + c0);
    const float* W4 = Wr + ((k8 * 8 + 4) * NF + c0);
    const float* W5 = Wr + ((k8 * 8 + 5) * NF + c0);
    const float* W6 = Wr + ((k8 * 8 + 6) * NF + c0);
    const float* W7 = Wr + ((k8 * 8 + 7) * NF + c0);
#pragma unroll
    for (int cc = 0; cc < 16; ++cc)
      acc[cc] += a0 * W0[cc] + a1 * W1[cc] + a2 * W2[cc] + a3 * W3[cc]
               + a4 * W4[cc] + a5 * W5[cc] + a6 * W6[cc] + a7 * W7[cc];
  }

  if (valid) {
    uint4 b0, b1v;
    b0.x = (unsigned)f2bf(acc[0]) | ((unsigned)f2bf(acc[1]) << 16);
    b0.y = (unsigned)f2bf(acc[2]) | ((unsigned)f2bf(acc[3]) << 16);
    b0.z = (unsigned)f2bf(acc[4]) | ((unsigned)f2bf(acc[5]) << 16);
    b0.w = (unsigned)f2bf(acc[6]) | ((unsigned)f2bf(acc[7]) << 16);
    b1v.x = (unsigned)f2bf(acc[8]) | ((unsigned)f2bf(acc[9]) << 16);
    b1v.y = (unsigned)f2bf(acc[10]) | ((unsigned)f2bf(acc[11]) << 16);
    b1v.z = (unsigned)f2bf(acc[12]) | ((unsigned)f2bf(acc[13]) << 16);
    b1v.w = (unsigned)f2bf(acc[14]) | ((unsigned)f2bf(acc[15]) << 16);
    uint4* obp = (uint4*)&outb[(size_t)row * NF + c0];
    obp[0] = b0;
    obp[1] = b1v;
  }

  float s = 0.f, q = 0.f;
#pragma unroll
  for (int cc = 0; cc < 16; ++cc) { s += acc[cc]; q += acc[cc] * acc[cc]; }
  sh_s[wv][lane] = s;
  sh_q[wv][lane] = q;
  __syncthreads();
  if (tid < 64) {
    float ss = sh_s[0][lane] + sh_s[1][lane] + sh_s[2][lane] + sh_s[3][lane];
    float qq = sh_q[0][lane] + sh_q[1][lane] + sh_q[2][lane] + sh_q[3][lane];
    int r = blockIdx.x * 64 + lane;
    if (r < NN) {
      int g = batch[r];
      atomicAdd(&gs[g], ss);
      atomicAdd(&gq[g], qq);
    }
  }
  __syncthreads();
  if (tid < NG) {
    float fs = gs[tid], fq = gq[tid];
    if (fs != 0.f || fq != 0.f) { atomicAdd(&gsum[tid], fs); atomicAdd(&gsq[tid], fq); }
  }
}

// ============ skip0: two sequential 16-acc passes (no register blowup) ============
// pass1: z1b = LN0(t0b)+PReLU + xb@W0 ; pass2: xs1b = xb@W1 (X rows L1-hot)
__global__ __launch_bounds__(256) void k_skip0(
    const ushortT* __restrict__ X,
    const float* __restrict__ W0p, const float* __restrict__ W1p,
    const ushortT* __restrict__ t0b,
    const float* __restrict__ gsum0, const float* __restrict__ gsq0,
    const float* __restrict__ lw0, const float* __restrict__ lb0, const float* __restrict__ pa0,
    const int* __restrict__ batch, const int* __restrict__ bound,
    ushortT* __restrict__ z1b, ushortT* __restrict__ xs1b) {
  int tid = threadIdx.x;
  int lane = tid & 63;
  int wv = __builtin_amdgcn_readfirstlane(tid >> 6);
  int c0 = wv * 16;
  int row = blockIdx.x * 64 + lane;
  bool valid = row < NN;
  int rsafe = valid ? row : 0;
  const ushortT* Xr = X + (size_t)rsafe * NF;

  float acc[16];
#pragma unroll
  for (int cc = 0; cc < 16; ++cc) acc[cc] = 0.f;

  // ---- pass 1: xb @ W0 ----
  for (int k8 = 0; k8 < 8; ++k8) {
    uint4 xv = *(const uint4*)&Xr[k8 * 8];
    float a0 = bflo(xv.x), a1 = bfhi(xv.x), a2 = bflo(xv.y), a3 = bfhi(xv.y);
    float a4 = bflo(xv.z), a5 = bfhi(xv.z), a6 = bflo(xv.w), a7 = bfhi(xv.w);
    const float* P0 = W0p + ((k8 * 8 + 0) * NF + c0);
    const float* P1 = W0p + ((k8 * 8 + 1) * NF + c0);
    const float* P2 = W0p + ((k8 * 8 + 2) * NF + c0);
    const float* P3 = W0p + ((k8 * 8 + 3) * NF + c0);
    const float* P4 = W0p + ((k8 * 8 + 4) * NF + c0);
    const float* P5 = W0p + ((k8 * 8 + 5) * NF + c0);
    const float* P6 = W0p + ((k8 * 8 + 6) * NF + c0);
    const float* P7 = W0p + ((k8 * 8 + 7) * NF + c0);
#pragma unroll
    for (int cc = 0; cc < 16; ++cc)
      acc[cc] += a0 * P0[cc] + a1 * P1[cc] + a2 * P2[cc] + a3 * P3[cc]
               + a4 * P4[cc] + a5 * P5[cc] + a6 * P6[cc] + a7 * P7[cc];
  }

  // LN0 residual + PReLU
  int g = batch[rsafe];
  float cntf = (float)(bound[g + 1] - bound[g]);
  float norm = fmaxf(cntf, 1.f) * (float)NF;
  float m0 = gsum0[g] / norm;
  float v0 = gsq0[g] / norm - m0 * m0;
  float rs0 = rsqrtf(v0 + EPSV);
  float a0p = pa0[0];
  const uint4* T0 = (const uint4*)(t0b + (size_t)rsafe * NF + c0);
#pragma unroll
  for (int j = 0; j < 2; ++j) {
    uint4 tv = T0[j];
    float tvv[8] = {bflo(tv.x), bfhi(tv.x), bflo(tv.y), bfhi(tv.y),
                    bflo(tv.z), bfhi(tv.z), bflo(tv.w), bfhi(tv.w)};
#pragma unroll
    for (int jj = 0; jj < 8; ++jj) {
      int cc = j * 8 + jj;
      float u = (tvv[jj] - m0) * rs0 * lw0[c0 + cc] + lb0[c0 + cc];
      acc[cc] += (u >= 0.f) ? u : a0p * u;
    }
  }

  if (valid) {
    uint4 o0, o1;
    o0.x = (unsigned)f2bf(acc[0]) | ((unsigned)f2bf(acc[1]) << 16);
    o0.y = (unsigned)f2bf(acc[2]) | ((unsigned)f2bf(acc[3]) << 16);
    o0.z = (unsigned)f2bf(acc[4]) | ((unsigned)f2bf(acc[5]) << 16);
    o0.w = (unsigned)f2bf(acc[6]) | ((unsigned)f2bf(acc[7]) << 16);
    o1.x = (unsigned)f2bf(acc[8]) | ((unsigned)f2bf(acc[9]) << 16);
    o1.y = (unsigned)f2bf(acc[10]) | ((unsigned)f2bf(acc[11]) << 16);
    o1.z = (unsigned)f2bf(acc[12]) | ((unsigned)f2bf(acc[13]) << 16);
    o1.w = (unsigned)f2bf(acc[14]) | ((unsigned)f2bf(acc[15]) << 16);
    uint4* zp = (uint4*)&z1b[(size_t)row * NF + c0];
    zp[0] = o0; zp[1] = o1;
  }

  // ---- pass 2: xb @ W1 (rows L1-hot) ----
#pragma unroll
  for (int cc = 0; cc < 16; ++cc) acc[cc] = 0.f;
  for (int k8 = 0; k8 < 8; ++k8) {
    uint4 xv = *(const uint4*)&Xr[k8 * 8];
    float a0 = bflo(xv.x), a1 = bfhi(xv.x), a2 = bflo(xv.y), a3 = bfhi(xv.y);
    float a4 = bflo(xv.z), a5 = bfhi(xv.z), a6 = bflo(xv.w), a7 = bfhi(xv.w);
    const float* Q0 = W1p + ((k8 * 8 + 0) * NF + c0);
    const float* Q1 = W1p + ((k8 * 8 + 1) * NF + c0);
    const float* Q2 = W1p + ((k8 * 8 + 2) * NF + c0);
    const float* Q3 = W1p + ((k8 * 8 + 3) * NF + c0);
    const float* Q4 = W1p + ((k8 * 8 + 4) * NF + c0);
    const float* Q5 = W1p + ((k8 * 8 + 5) * NF + c0);
    const float* Q6 = W1p + ((k8 * 8 + 6) * NF + c0);
    const float* Q7 = W1p + ((k8 * 8 + 7) * NF + c0);
#pragma unroll
    for (int cc = 0; cc < 16; ++cc)
      acc[cc] += a0 * Q0[cc] + a1 * Q1[cc] + a2 * Q2[cc] + a3 * Q3[cc]
               + a4 * Q4[cc] + a5 * Q5[cc] + a6 * Q6[cc] + a7 * Q7[cc];
  }
  if (valid) {
    uint4 s0v, s1v;
    s0v.x = (unsigned)f2bf(acc[0]) | ((unsigned)f2bf(acc[1]) << 16);
    s0v.y = (unsigned)f2bf(acc[2]) | ((unsigned)f2bf(acc[3]) << 16);
    s0v.z = (unsigned)f2bf(acc[4]) | ((unsigned)f2bf(acc[5]) << 16);
    s0v.w = (unsigned)f2bf(acc[6]) | ((unsigned)f2bf(acc[7]) << 16);
    s1v.x = (unsigned)f2bf(acc[8]) | ((unsigned)f2bf(acc[9]) << 16);
    s1v.y = (unsigned)f2bf(acc[10]) | ((unsigned)f2bf(acc[11]) << 16);
    s1v.z = (unsigned)f2bf(acc[12]) | ((unsigned)f2bf(acc[13]) << 16);
    s1v.w = (unsigned)f2bf(acc[14]) | ((unsigned)f2bf(acc[15]) << 16);
    uint4* sp = (uint4*)&xs1b[(size_t)row * NF + c0];
    sp[0] = s0v; sp[1] = s1v;
  }
}

// ============ skip1 (elementwise): z2b = PReLU0(LN0(h1b)) + PReLU1(LN1(h2b)) + xs1b ============
__global__ __launch_bounds__(256) void k_skip1(
    const ushortT* __restrict__ h1b, const ushortT* __restrict__ h2b,
    const ushortT* __restrict__ xs1b,
    const float* __restrict__ gsum0, const float* __restrict__ gsq0,
    const float* __restrict__ lw0, const float* __restrict__ lb0, const float* __restrict__ pa0,
    const float* __restrict__ gsum1, const float* __restrict__ gsq1,
    const float* __restrict__ lw1, const float* __restrict__ lb1, const float* __restrict__ pa1,
    const int* __restrict__ batch, const int* __restrict__ bound,
    ushortT* __restrict__ z2b) {
  int t = blockIdx.x * 256 + threadIdx.x;   // one uint4 (8 bf16) per thread
  if (t >= NN * NF / 8) return;
  int row = t >> 3;
  int f0 = (t & 7) * 8;
  int g = batch[row];
  float cntf = (float)(bound[g + 1] - bound[g]);
  float norm = fmaxf(cntf, 1.f) * (float)NF;
  float m0 = gsum0[g] / norm;
  float va0 = gsq0[g] / norm - m0 * m0;
  float rs0 = rsqrtf(va0 + EPSV);
  float m1 = gsum1[g] / norm;
  float va1 = gsq1[g] / norm - m1 * m1;
  float rs1 = rsqrtf(va1 + EPSV);
  float a0 = pa0[0], a1 = pa1[0];
  uint4 h1 = ((const uint4*)h1b)[t];
  uint4 h2 = ((const uint4*)h2b)[t];
  uint4 xs = ((const uint4*)xs1b)[t];
  float r[8];
  float h1v[8] = {bflo(h1.x), bfhi(h1.x), bflo(h1.y), bfhi(h1.y),
                  bflo(h1.z), bfhi(h1.z), bflo(h1.w), bfhi(h1.w)};
  float h2v[8] = {bflo(h2.x), bfhi(h2.x), bflo(h2.y), bfhi(h2.y),
                  bflo(h2.z), bfhi(h2.z), bflo(h2.w), bfhi(h2.w)};
  float xsv[8] = {bflo(xs.x), bfhi(xs.x), bflo(xs.y), bfhi(xs.y),
                  bflo(xs.z), bfhi(xs.z), bflo(xs.w), bfhi(xs.w)};
#pragma unroll
  for (int j = 0; j < 8; ++j) {
    float u = (h1v[j] - m0) * rs0 * lw0[f0 + j] + lb0[f0 + j];
    u = (u >= 0.f) ? u : a0 * u;
    float w = (h2v[j] - m1) * rs1 * lw1[f0 + j] + lb1[f0 + j];
    w = (w >= 0.f) ? w : a1 * w;
    r[j] = u + w + xsv[j];
  }
  uint4 o;
  o.x = (unsigned)f2bf(r[0]) | ((unsigned)f2bf(r[1]) << 16);
  o.y = (unsigned)f2bf(r[2]) | ((unsigned)f2bf(r[3]) << 16);
  o.z = (unsigned)f2bf(r[4]) | ((unsigned)f2bf(r[5]) << 16);
  o.w = (unsigned)f2bf(r[6]) | ((unsigned)f2bf(r[7]) << 16);
  ((uint4*)z2b)[t] = o;
}

// ============ graph LayerNorm apply + affine + PReLU (final layer, bf16 in, fp32 out) ============
__global__ __launch_bounds__(256) void k_ln_apply(const ushortT* __restrict__ t,
                                                  const int* __restrict__ batch,
                                                  const int* __restrict__ bound,
                                                  const float* __restrict__ gsum,
                                                  const float* __restrict__ gsq,
                                                  const float* __restrict__ w,
                                                  const float* __restrict__ b,
                                                  const float* __restrict__ alpha,
                                                  float* __restrict__ out) {
  int wid = (blockIdx.x * 256 + threadIdx.x) >> 6;
  int lane = threadIdx.x & 63;
  if (wid >= NN) return;
  int g = batch[wid];
  float cnt = (float)(bound[g + 1] - bound[g]);
  float norm = fmaxf(cnt, 1.f) * (float)NF;
  float mean = gsum[g] / norm;
  float var = gsq[g] / norm - mean * mean;
  float rstd = rsqrtf(var + EPSV);
  float a = alpha[0];
  float v = __uint_as_float(((unsigned)t[(size_t)wid * NF + lane]) << 16);
  v = (v - mean) * rstd;
  v = v * w[lane] + b[lane];
  out[(size_t)wid * NF + lane] = (v >= 0.f) ? v : a * v;
}

// ======================= launch =======================
extern "C" void kernel_launch(void* const* d_in, const int* in_sizes, int n_in,
                              void* d_out, int out_size, void* d_ws, size_t ws_size,
                              hipStream_t stream) {
  const float* x     = (const float*)d_in[0];
  const float* c0_Wl = (const float*)d_in[1];
  const float* c0_bl = (const float*)d_in[2];
  const float* c0_Wr = (const float*)d_in[3];
  const float* c1_Wl = (const float*)d_in[4];
  const float* c1_bl = (const float*)d_in[5];
  const float* c1_Wr = (const float*)d_in[6];
  const float* c2_Wl = (const float*)d_in[7];
  const float* c2_bl = (const float*)d_in[8];
  const float* c2_Wr = (const float*)d_in[9];
  const float* s0_W  = (const float*)d_in[10];
  const float* s1_W  = (const float*)d_in[11];
  const float* ln0_w = (const float*)d_in[12];
  const float* ln0_b = (const float*)d_in[13];
  const float* ln1_w = (const float*)d_in[14];
  const float* ln1_b = (const float*)d_in[15];
  const float* ln2_w = (const float*)d_in[16];
  const float* ln2_b = (const float*)d_in[17];
  const float* p0_a  = (const float*)d_in[18];
  const float* p1_a  = (const float*)d_in[19];
  const float* p2_a  = (const float*)d_in[20];
  const int*   ei    = (const int*)d_in[21];   // [2, E] int32
  const int*   batch = (const int*)d_in[22];   // [N] int32
  float* out = (float*)d_out;

  const int* src = ei;
  const int* dst = ei + NE;

  // ---- workspace layout ----
  char* ws = (char*)d_ws;
  const size_t off_gcur   = 0;                          // NBUCK ints
  const size_t off_stats  = 4096;                       // 6*G floats
  const size_t off_bound  = 8192;                       // G+1 ints
  const size_t off_od     = 12288;                      // N ints (packed off|deg)
  const size_t off_csr    = 262144;                     // NBUCK*BCAP ints = 4014080
  const size_t off_bbuf   = 4980736;                    // NBUCK*BCAP ints (packed edges)
  const size_t off_B1b    = off_bbuf;                   // agg out bf16 (aliases bbuf)
  const size_t off_B2b    = 13631488;                   // h1 raw bf16 6.4MB
  const size_t off_B4b    = off_B2b + 6400000;          // h2 raw bf16
  const size_t off_xb     = off_B4b + 6400000;          // x bf16
  const size_t off_B3b    = off_xb + 6400000;           // z bf16
  const size_t off_xs1b   = off_B3b + 6400000;          // x@s1_W bf16 / out raw bf16

  int*    gcursor = (int*)(ws + off_gcur);
  float*  stats   = (float*)(ws + off_stats);
  int*    bound   = (int*)(ws + off_bound);
  int*    offdeg  = (int*)(ws + off_od);
  int*    csr     = (int*)(ws + off_csr);
  int*    bbuf    = (int*)(ws + off_bbuf);
  ushortT* B1b    = (ushortT*)(ws + off_B1b);
  ushortT* B2b    = (ushortT*)(ws + off_B2b);
  ushortT* B4b    = (ushortT*)(ws + off_B4b);
  ushortT* xb     = (ushortT*)(ws + off_xb);
  ushortT* B3b    = (ushortT*)(ws + off_B3b);
  ushortT* xs1b   = (ushortT*)(ws + off_xs1b);
  (void)ws_size; (void)in_sizes; (void)n_in; (void)out_size;

  float* gsum0 = stats + 0 * NG; float* gsq0 = stats + 1 * NG;
  float* gsum1 = stats + 2 * NG; float* gsq1 = stats + 3 * NG;
  float* gsum2 = stats + 4 * NG; float* gsq2 = stats + 5 * NG;

  const int WB  = (NN * 64 + 255) / 256;       // 12500 (wave-per-node)
  const int CB  = (NN * NF / 4 + 255) / 256;   // 3125  (pre)
  const int EWB = (NN * NF / 8 + 255) / 256;   // 1563  (skip1 elementwise)

  // pre (cvt + bounds + zero) and bucketed CSR build
  k_pre<<<CB, 256, 0, stream>>>(x, xb, batch, bound, gcursor, stats);
  k_binA<<<NBUCK, 256, 0, stream>>>(src, dst, gcursor, bbuf);
  k_binB<<<NBUCK, 256, 0, stream>>>(bbuf, gcursor, offdeg, csr);

  // ---- layer 0 ----
  k_agg<<<WB, 256, 0, stream>>>(xb, offdeg, csr, B1b);
  k_sage_linear<<<GB3, 256, 0, stream>>>(B1b, xb, c0_Wl, c0_bl, c0_Wr,
                                         batch, gsum0, gsq0, B2b);
  // z1b = LN0(B2b)+PReLU + xb@s0_W ; xs1b = xb@s1_W
  k_skip0<<<GB3, 256, 0, stream>>>(xb, s0_W, s1_W,
                                   B2b, gsum0, gsq0, ln0_w, ln0_b, p0_a,
                                   batch, bound, B3b, xs1b);

  // ---- layer 1 ----
  k_agg<<<WB, 256, 0, stream>>>(B3b, offdeg, csr, B1b);
  k_sage_linear<<<GB3, 256, 0, stream>>>(B1b, B3b, c1_Wl, c1_bl, c1_Wr,
                                         batch, gsum1, gsq1, B4b);
  // z2b = PReLU0(LN0(B2b)) + PReLU1(LN1(B4b)) + xs1b
  k_skip1<<<EWB, 256, 0, stream>>>(B2b, B4b, xs1b,
                                   gsum0, gsq0, ln0_w, ln0_b, p0_a,
                                   gsum1, gsq1, ln1_w, ln1_b, p1_a,
                                   batch, bound, B3b);

  // ---- layer 2 ----  (xs1b is dead after skip1 -> reuse for raw out bf16)
  k_agg<<<WB, 256, 0, stream>>>(B3b, offdeg, csr, B1b);
  k_sage_linear<<<GB3, 256, 0, stream>>>(B1b, B3b, c2_Wl, c2_bl, c2_Wr,
                                         batch, gsum2, gsq2, xs1b);
  k_ln_apply<<<WB, 256, 0, stream>>>(xs1b, batch, bound, gsum2, gsq2, ln2_w, ln2_b, p2_a, out);
}